// Round 4
// baseline (698.700 us; speedup 1.0000x reference)
//
#include <hip/hip_runtime.h>

#define HW 3136
#define NPOS 100352.0f

typedef unsigned short ushortT;
typedef __attribute__((ext_vector_type(8))) short short8;
typedef __attribute__((ext_vector_type(4))) float floatx4;

__device__ inline float bf2f(ushortT u) {
    union { unsigned int i; float f; } v; v.i = ((unsigned int)u) << 16; return v.f;
}
__device__ inline ushortT f2bf(float f) {
    union { float f; unsigned int i; } v; v.f = f;
    unsigned int r = v.i + 0x7FFFu + ((v.i >> 16) & 1u);
    return (ushortT)(r >> 16);
}

// ---------- prep: convert weights to bf16 (+ w3 reswizzle), zero stat sums ----------
__global__ __launch_bounds__(256) void prep_k(const float* __restrict__ w1,
                                              const float* __restrict__ w3,
                                              const float* __restrict__ wa,
                                              ushortT* __restrict__ w1b,
                                              ushortT* __restrict__ wab,
                                              ushortT* __restrict__ w3b,
                                              float* __restrict__ sums_all) {
    int i = blockIdx.x * 256 + threadIdx.x;
    if (i < 131072) { w1b[i] = f2bf(w1[i]); wab[i] = f2bf(wa[i]); }
    if (i < 81920) {
        // w3b[g][s 0..9][oc][ic], s==9 is a zero pad (dummy MFMA half)
        int ic = i & 15, oc = (i >> 4) & 15, rest = i >> 8;
        int s = rest % 10, g = rest / 10;
        w3b[i] = (s < 9) ? f2bf(w3[(((g * 16 + oc) * 16) + ic) * 9 + s]) : (ushortT)0;
    }
    if (i < 2560) sums_all[i] = 0.f;
}

// ---------- transpose x: [n][k 256][p 3136] f32 -> xb [n][p][k] bf16 ----------------
__global__ __launch_bounds__(256) void transx_k(const float* __restrict__ x,
                                                ushortT* __restrict__ xb) {
    __shared__ float tf[64 * 65];
    const int t = threadIdx.x;
    const int p0 = blockIdx.x * 64, k0 = blockIdx.y * 64, n = blockIdx.z;
#pragma unroll
    for (int i = 0; i < 16; i++) {
        int idx = t + i * 256;
        int k = idx >> 6, p = idx & 63;
        tf[k * 65 + p] = x[((size_t)n * 256 + k0 + k) * HW + p0 + p];
    }
    __syncthreads();
#pragma unroll
    for (int i = 0; i < 2; i++) {
        int idx = t + i * 256;
        int p = idx >> 3, kq = (idx & 7) * 8;
        short8 o;
#pragma unroll
        for (int j = 0; j < 8; j++) o[j] = (short)f2bf(tf[(kq + j) * 65 + p]);
        *(short8*)&xb[((size_t)n * HW + p0 + p) * 256 + k0 + kq] = o;
    }
}

// ---------- MFMA GEMM1 + fused stats1 -----------------------------------------------
__global__ __launch_bounds__(256) void gemm1_k(const ushortT* __restrict__ xb,
                                               const ushortT* __restrict__ w1b,
                                               ushortT* __restrict__ t1,
                                               float* __restrict__ sums1) {
    __shared__ ushortT As[128 * 40];
    __shared__ ushortT Bs[128 * 40];
    const int t = threadIdx.x;
    const int P0 = blockIdx.x * 128, C0 = blockIdx.y * 128, n = blockIdx.z;
    const int w = t >> 6, lane = t & 63;
    const int mh = (w >> 1) * 64, nh = (w & 1) * 64;
    const int l15 = lane & 15, quad = lane >> 4;
    const int sr = t >> 2, skq = (t & 3) * 8;

    floatx4 acc[4][4];
#pragma unroll
    for (int a = 0; a < 4; a++)
#pragma unroll
        for (int b = 0; b < 4; b++)
#pragma unroll
            for (int e = 0; e < 4; e++) acc[a][b][e] = 0.f;

    for (int kb = 0; kb < 256; kb += 32) {
#pragma unroll
        for (int i = 0; i < 2; i++) {
            int r = sr + i * 64;
            short8 v = *(const short8*)&w1b[(size_t)(C0 + r) * 256 + kb + skq];
            *(short8*)&As[r * 40 + skq] = v;
        }
#pragma unroll
        for (int i = 0; i < 2; i++) {
            int p = sr + i * 64;
            short8 v;
            if (P0 + p < HW) {
                v = *(const short8*)&xb[((size_t)n * HW + P0 + p) * 256 + kb + skq];
            } else {
#pragma unroll
                for (int j = 0; j < 8; j++) v[j] = 0;
            }
            *(short8*)&Bs[p * 40 + skq] = v;
        }
        __syncthreads();
        short8 af[4], bf[4];
#pragma unroll
        for (int mt = 0; mt < 4; mt++)
            af[mt] = *(const short8*)&As[(mh + mt * 16 + l15) * 40 + quad * 8];
#pragma unroll
        for (int nt = 0; nt < 4; nt++)
            bf[nt] = *(const short8*)&Bs[(nh + nt * 16 + l15) * 40 + quad * 8];
#pragma unroll
        for (int mt = 0; mt < 4; mt++)
#pragma unroll
            for (int nt = 0; nt < 4; nt++)
                acc[mt][nt] = __builtin_amdgcn_mfma_f32_16x16x32_bf16(af[mt], bf[nt], acc[mt][nt], 0, 0, 0);
        __syncthreads();
    }
#pragma unroll
    for (int mt = 0; mt < 4; mt++) {
        int c = C0 + mh + mt * 16 + quad * 4;
#pragma unroll
        for (int nt = 0; nt < 4; nt++) {
            int pp = P0 + nh + nt * 16 + l15;
            if (pp < HW) {
                ushort4 o;
                o.x = f2bf(acc[mt][nt][0]); o.y = f2bf(acc[mt][nt][1]);
                o.z = f2bf(acc[mt][nt][2]); o.w = f2bf(acc[mt][nt][3]);
                *(ushort4*)&t1[((size_t)n * HW + pp) * 512 + c] = o;
            }
        }
    }
    // fused stats1 (OOB positions contributed acc==0 -> no effect)
#pragma unroll
    for (int mt = 0; mt < 4; mt++) {
        int c = C0 + mh + mt * 16 + quad * 4;
#pragma unroll
        for (int e = 0; e < 4; e++) {
            float sv = acc[mt][0][e] + acc[mt][1][e] + acc[mt][2][e] + acc[mt][3][e];
            float qv = acc[mt][0][e] * acc[mt][0][e] + acc[mt][1][e] * acc[mt][1][e]
                     + acc[mt][2][e] * acc[mt][2][e] + acc[mt][3][e] * acc[mt][3][e];
            sv += __shfl_xor(sv, 1); qv += __shfl_xor(qv, 1);
            sv += __shfl_xor(sv, 2); qv += __shfl_xor(qv, 2);
            sv += __shfl_xor(sv, 4); qv += __shfl_xor(qv, 4);
            sv += __shfl_xor(sv, 8); qv += __shfl_xor(qv, 8);
            if (l15 == 0) {
                atomicAdd(&sums1[c + e], sv);
                atomicAdd(&sums1[512 + c + e], qv);
            }
        }
    }
}

// ---------- gconv: 4 groups/block, coalesced 128B reads, fused BN1+ReLU + stats2 ----
__global__ __launch_bounds__(256) void gconv_k(const ushortT* __restrict__ t1,
                                               const ushortT* __restrict__ w3b,
                                               const float* __restrict__ sums1,
                                               const float* __restrict__ g1,
                                               const float* __restrict__ b1,
                                               ushortT* __restrict__ t2,
                                               float* __restrict__ sums2) {
    // 8 planes (chq) x 590 pos (10 rows x 59 padded cols) x 8 ch; 16B-aligned frags
    __shared__ ushortT tile[8 * 590 * 8];
    __shared__ float scs[64], shs[64];
    const int t = threadIdx.x;
    const int rt = blockIdx.x, gg = blockIdx.y, n = blockIdx.z;
    const int r0 = rt * 8;

    if (t < 64) {
        int c = gg * 64 + t;
        float m = sums1[c] * (1.f / NPOS);
        float var = sums1[512 + c] * (1.f / NPOS) - m * m;
        float sc = g1[c] * rsqrtf(var + 1e-5f);
        scs[t] = sc; shs[t] = b1[c] - m * sc;
    }
    __syncthreads();

    const int chq = t & 7;
    float sc8[8], sh8[8];
#pragma unroll
    for (int j = 0; j < 8; j++) { sc8[j] = scs[chq * 8 + j]; sh8[j] = shs[chq * 8 + j]; }

    const ushortT* src = t1 + (size_t)n * HW * 512 + gg * 64 + chq * 8;
    for (int idx = t; idx < 4640; idx += 256) {
        int pos = idx >> 3;
        int row = pos / 58, col = pos - row * 58;   // row 0..9, col 0..57
        int ir = r0 - 1 + row, icl = col - 1;
        short8 o;
        if (ir >= 0 && ir < 56 && icl >= 0 && icl < 56) {
            short8 v = *(const short8*)&src[(size_t)(ir * 56 + icl) * 512];
#pragma unroll
            for (int j = 0; j < 8; j++)
                o[j] = (short)f2bf(fmaxf(fmaf(sc8[j], bf2f((ushortT)v[j]), sh8[j]), 0.f));
        } else {
#pragma unroll
            for (int j = 0; j < 8; j++) o[j] = 0;
        }
        *(short8*)&tile[((chq * 590) + row * 59 + col) * 8] = o;
    }
    __syncthreads();

    const int w = t >> 6, lane = t & 63;
    const int l15 = lane & 15, quad = lane >> 4;
    const int qh = quad >> 1, ql = quad & 1;
    const int g = gg * 4 + w;                  // wave owns one group

    short8 af[5];
    int drv[5], dcv[5];
#pragma unroll
    for (int s = 0; s < 5; s++) {
        int shift = 2 * s + qh;
        af[s] = *(const short8*)&w3b[((g * 10 + shift) * 16 + l15) * 16 + ql * 8];
        if (shift == 9) shift = 8;             // dummy half: valid addr, zero weights
        drv[s] = shift / 3; dcv[s] = shift - drv[s] * 3;
    }

    const int pr = l15 >> 2, pc = l15 & 3;
    const int plane = (w * 2 + ql) * 590;
    float s4[4] = {0.f, 0.f, 0.f, 0.f}, q4[4] = {0.f, 0.f, 0.f, 0.f};

#pragma unroll
    for (int rh = 0; rh < 2; rh++) {
        const int rbase = rh * 4 + pr;
        floatx4 acc[14];
#pragma unroll
        for (int ct = 0; ct < 14; ct++)
#pragma unroll
            for (int e = 0; e < 4; e++) acc[ct][e] = 0.f;

#pragma unroll
        for (int ct = 0; ct < 14; ct++) {
            int colb = ct * 4 + pc;
#pragma unroll
            for (int s = 0; s < 5; s++) {
                short8 bfv = *(const short8*)&tile[(plane + (rbase + drv[s]) * 59 + colb + dcv[s]) * 8];
                acc[ct] = __builtin_amdgcn_mfma_f32_16x16x32_bf16(af[s], bfv, acc[ct], 0, 0, 0);
            }
        }
#pragma unroll
        for (int ct = 0; ct < 14; ct++) {
            int pos = (r0 + rh * 4 + pr) * 56 + ct * 4 + pc;
            ushort4 o;
            o.x = f2bf(acc[ct][0]); o.y = f2bf(acc[ct][1]);
            o.z = f2bf(acc[ct][2]); o.w = f2bf(acc[ct][3]);
            *(ushort4*)&t2[((size_t)n * HW + pos) * 512 + g * 16 + quad * 4] = o;
#pragma unroll
            for (int e = 0; e < 4; e++) {
                float a = acc[ct][e];
                s4[e] += a; q4[e] += a * a;
            }
        }
    }
#pragma unroll
    for (int e = 0; e < 4; e++) {
        float sv = s4[e], qv = q4[e];
        sv += __shfl_xor(sv, 1); qv += __shfl_xor(qv, 1);
        sv += __shfl_xor(sv, 2); qv += __shfl_xor(qv, 2);
        sv += __shfl_xor(sv, 4); qv += __shfl_xor(qv, 4);
        sv += __shfl_xor(sv, 8); qv += __shfl_xor(qv, 8);
        if (l15 == 0) {
            atomicAdd(&sums2[g * 16 + quad * 4 + e], sv);
            atomicAdd(&sums2[512 + g * 16 + quad * 4 + e], qv);
        }
    }
}

// ---------- MFMA GEMM3: full 256-ch tile, fused BN2+ReLU on input + stats3 ----------
__global__ __launch_bounds__(256) void gemm3_k(const ushortT* __restrict__ t2,
                                               const ushortT* __restrict__ wab,
                                               const float* __restrict__ sums2,
                                               const float* __restrict__ g3,
                                               const float* __restrict__ b3,
                                               ushortT* __restrict__ t3,
                                               float* __restrict__ sums3) {
    __shared__ ushortT As[256 * 40];
    __shared__ ushortT Bs[64 * 40];
    __shared__ float2 scsh[512];
    const int t = threadIdx.x;
    const int P0 = blockIdx.x * 64, n = blockIdx.y;   // 49*64 == 3136 exactly, no OOB
    const int w = t >> 6, lane = t & 63;
    const int mh = w * 64;
    const int l15 = lane & 15, quad = lane >> 4;
    const int sr = t >> 2, skq = (t & 3) * 8;

#pragma unroll
    for (int i = 0; i < 2; i++) {
        int c = t + i * 256;
        float m = sums2[c] * (1.f / NPOS);
        float var = sums2[512 + c] * (1.f / NPOS) - m * m;
        float sc = g3[c] * rsqrtf(var + 1e-5f);
        scsh[c] = make_float2(sc, b3[c] - m * sc);
    }
    __syncthreads();

    floatx4 acc[4][4];
#pragma unroll
    for (int a = 0; a < 4; a++)
#pragma unroll
        for (int b = 0; b < 4; b++)
#pragma unroll
            for (int e = 0; e < 4; e++) acc[a][b][e] = 0.f;

    for (int kb = 0; kb < 512; kb += 32) {
#pragma unroll
        for (int i = 0; i < 4; i++) {
            int r = sr + i * 64;
            short8 v = *(const short8*)&wab[(size_t)r * 512 + kb + skq];
            *(short8*)&As[r * 40 + skq] = v;
        }
        {
            int p = sr;
            short8 v = *(const short8*)&t2[((size_t)n * HW + P0 + p) * 512 + kb + skq];
            short8 o;
#pragma unroll
            for (int j = 0; j < 8; j++) {
                float2 ss = scsh[kb + skq + j];
                o[j] = (short)f2bf(fmaxf(fmaf(ss.x, bf2f((ushortT)v[j]), ss.y), 0.f));
            }
            *(short8*)&Bs[p * 40 + skq] = o;
        }
        __syncthreads();
        short8 af[4], bf[4];
#pragma unroll
        for (int mt = 0; mt < 4; mt++)
            af[mt] = *(const short8*)&As[(mh + mt * 16 + l15) * 40 + quad * 8];
#pragma unroll
        for (int nt = 0; nt < 4; nt++)
            bf[nt] = *(const short8*)&Bs[(nt * 16 + l15) * 40 + quad * 8];
#pragma unroll
        for (int mt = 0; mt < 4; mt++)
#pragma unroll
            for (int nt = 0; nt < 4; nt++)
                acc[mt][nt] = __builtin_amdgcn_mfma_f32_16x16x32_bf16(af[mt], bf[nt], acc[mt][nt], 0, 0, 0);
        __syncthreads();
    }
#pragma unroll
    for (int mt = 0; mt < 4; mt++) {
        int c = mh + mt * 16 + quad * 4;
#pragma unroll
        for (int nt = 0; nt < 4; nt++) {
            int pp = P0 + nt * 16 + l15;
            ushort4 o;
            o.x = f2bf(acc[mt][nt][0]); o.y = f2bf(acc[mt][nt][1]);
            o.z = f2bf(acc[mt][nt][2]); o.w = f2bf(acc[mt][nt][3]);
            *(ushort4*)&t3[((size_t)n * HW + pp) * 256 + c] = o;
        }
    }
#pragma unroll
    for (int mt = 0; mt < 4; mt++) {
        int c = mh + mt * 16 + quad * 4;
#pragma unroll
        for (int e = 0; e < 4; e++) {
            float sv = acc[mt][0][e] + acc[mt][1][e] + acc[mt][2][e] + acc[mt][3][e];
            float qv = acc[mt][0][e] * acc[mt][0][e] + acc[mt][1][e] * acc[mt][1][e]
                     + acc[mt][2][e] * acc[mt][2][e] + acc[mt][3][e] * acc[mt][3][e];
            sv += __shfl_xor(sv, 1); qv += __shfl_xor(qv, 1);
            sv += __shfl_xor(sv, 2); qv += __shfl_xor(qv, 2);
            sv += __shfl_xor(sv, 4); qv += __shfl_xor(qv, 4);
            sv += __shfl_xor(sv, 8); qv += __shfl_xor(qv, 8);
            if (l15 == 0) {
                atomicAdd(&sums3[c + e], sv);
                atomicAdd(&sums3[256 + c + e], qv);
            }
        }
    }
}

// ---------- final: out[n][c][p] = relu(bn3(t3[n][p][c]) + x[n][c][p]) ---------------
__global__ __launch_bounds__(256) void final_k(const ushortT* __restrict__ t3,
                                               const float* __restrict__ x,
                                               const float* __restrict__ sums3,
                                               const float* __restrict__ ga,
                                               const float* __restrict__ ba,
                                               float* __restrict__ out) {
    __shared__ float tf[64 * 65];
    __shared__ float scs[64], shs[64];
    const int t = threadIdx.x;
    const int p0 = blockIdx.x * 64, c0 = blockIdx.y * 64, n = blockIdx.z;
    if (t < 64) {
        int c = c0 + t;
        float m = sums3[c] * (1.f / NPOS);
        float var = sums3[256 + c] * (1.f / NPOS) - m * m;
        float sc = ga[c] * rsqrtf(var + 1e-5f);
        scs[t] = sc; shs[t] = ba[c] - m * sc;
    }
    __syncthreads();
#pragma unroll
    for (int i = 0; i < 4; i++) {
        int idx = t + i * 256;
        int p = idx >> 4, cq = (idx & 15) * 4;
        ushort4 v = *(const ushort4*)&t3[((size_t)n * HW + p0 + p) * 256 + c0 + cq];
        tf[(cq + 0) * 65 + p] = fmaf(scs[cq + 0], bf2f(v.x), shs[cq + 0]);
        tf[(cq + 1) * 65 + p] = fmaf(scs[cq + 1], bf2f(v.y), shs[cq + 1]);
        tf[(cq + 2) * 65 + p] = fmaf(scs[cq + 2], bf2f(v.z), shs[cq + 2]);
        tf[(cq + 3) * 65 + p] = fmaf(scs[cq + 3], bf2f(v.w), shs[cq + 3]);
    }
    __syncthreads();
#pragma unroll
    for (int i = 0; i < 4; i++) {
        int idx = t + i * 256;
        int c = idx >> 4, pq = (idx & 15) * 4;
        size_t off = ((size_t)n * 256 + c0 + c) * HW + p0 + pq;
        float4 xv = *(const float4*)&x[off];
        float4 o;
        o.x = fmaxf(tf[c * 65 + pq + 0] + xv.x, 0.f);
        o.y = fmaxf(tf[c * 65 + pq + 1] + xv.y, 0.f);
        o.z = fmaxf(tf[c * 65 + pq + 2] + xv.z, 0.f);
        o.w = fmaxf(tf[c * 65 + pq + 3] + xv.w, 0.f);
        *(float4*)&out[off] = o;
    }
}

extern "C" void kernel_launch(void* const* d_in, const int* in_sizes, int n_in,
                              void* d_out, int out_size, void* d_ws, size_t ws_size,
                              hipStream_t stream) {
    const float* x  = (const float*)d_in[0];
    const float* w1 = (const float*)d_in[1];
    const float* g1 = (const float*)d_in[2];
    const float* b1 = (const float*)d_in[3];
    const float* w3 = (const float*)d_in[4];
    const float* g3 = (const float*)d_in[5];
    const float* b3 = (const float*)d_in[6];
    const float* wa = (const float*)d_in[7];
    const float* ga = (const float*)d_in[8];
    const float* ba = (const float*)d_in[9];
    float* out = (float*)d_out;

    char* ws = (char*)d_ws;
    // Region 1 (102,760,448 B): t1, later reused as t3
    ushortT* t1 = (ushortT*)ws;
    ushortT* t3 = t1;
    // Region 2 (102,760,448 B): xb (first 51 MB), later overwritten by t2
    ushortT* xb = (ushortT*)(ws + 102760448);
    ushortT* t2 = (ushortT*)(ws + 102760448);
    ushortT* w1b = (ushortT*)(ws + 205520896);
    ushortT* wab = (ushortT*)(ws + 205783040);
    ushortT* w3b = (ushortT*)(ws + 206045184);
    float* sums_all = (float*)(ws + 206209024);
    float* sums1 = sums_all;
    float* sums2 = sums_all + 1024;
    float* sums3 = sums_all + 2048;

    prep_k<<<512, 256, 0, stream>>>(w1, w3, wa, w1b, wab, w3b, sums_all);
    transx_k<<<dim3(49, 4, 32), 256, 0, stream>>>(x, xb);
    gemm1_k<<<dim3(25, 4, 32), 256, 0, stream>>>(xb, w1b, t1, sums1);
    gconv_k<<<dim3(7, 8, 32), 256, 0, stream>>>(t1, w3b, sums1, g1, b1, t2, sums2);
    gemm3_k<<<dim3(49, 32), 256, 0, stream>>>(t2, wab, sums2, g3, b3, t3, sums3);
    final_k<<<dim3(49, 4, 32), 256, 0, stream>>>(t3, x, sums3, ga, ba, out);
}

// Round 5
// 501.104 us; speedup vs baseline: 1.3943x; 1.3943x over previous
//
#include <hip/hip_runtime.h>

#define HW 3136
#define NPOS 100352.0f
#define NSLICE 32

typedef unsigned short ushortT;
typedef __attribute__((ext_vector_type(8))) short short8;
typedef __attribute__((ext_vector_type(4))) float floatx4;

__device__ inline float bf2f(ushortT u) {
    union { unsigned int i; float f; } v; v.i = ((unsigned int)u) << 16; return v.f;
}
__device__ inline ushortT f2bf(float f) {
    union { float f; unsigned int i; } v; v.f = f;
    unsigned int r = v.i + 0x7FFFu + ((v.i >> 16) & 1u);
    return (ushortT)(r >> 16);
}

// ---------- prep: convert weights to bf16 (+ w3 reswizzle), zero stat partials ------
// partials layout (floats): p1[32][1024] | p2[32][1024] | p3[32][512]  = 81920 floats
__global__ __launch_bounds__(256) void prep_k(const float* __restrict__ w1,
                                              const float* __restrict__ w3,
                                              const float* __restrict__ wa,
                                              ushortT* __restrict__ w1b,
                                              ushortT* __restrict__ wab,
                                              ushortT* __restrict__ w3b,
                                              float* __restrict__ partials) {
    int i = blockIdx.x * 256 + threadIdx.x;
    if (i < 131072) { w1b[i] = f2bf(w1[i]); wab[i] = f2bf(wa[i]); }
    if (i < 81920) {
        // w3b[g][s 0..9][oc][ic], s==9 is a zero pad (dummy MFMA half)
        int ic = i & 15, oc = (i >> 4) & 15, rest = i >> 8;
        int s = rest % 10, g = rest / 10;
        w3b[i] = (s < 9) ? f2bf(w3[(((g * 16 + oc) * 16) + ic) * 9 + s]) : (ushortT)0;
        partials[i] = 0.f;
    }
}

// ---------- transpose x: [n][k 256][p 3136] f32 -> xb [n][p][k] bf16 ----------------
__global__ __launch_bounds__(256) void transx_k(const float* __restrict__ x,
                                                ushortT* __restrict__ xb) {
    __shared__ float tf[64 * 65];
    const int t = threadIdx.x;
    const int p0 = blockIdx.x * 64, k0 = blockIdx.y * 64, n = blockIdx.z;
#pragma unroll
    for (int i = 0; i < 16; i++) {
        int idx = t + i * 256;
        int k = idx >> 6, p = idx & 63;
        tf[k * 65 + p] = x[((size_t)n * 256 + k0 + k) * HW + p0 + p];
    }
    __syncthreads();
#pragma unroll
    for (int i = 0; i < 2; i++) {
        int idx = t + i * 256;
        int p = idx >> 3, kq = (idx & 7) * 8;
        short8 o;
#pragma unroll
        for (int j = 0; j < 8; j++) o[j] = (short)f2bf(tf[(kq + j) * 65 + p]);
        *(short8*)&xb[((size_t)n * HW + p0 + p) * 256 + k0 + kq] = o;
    }
}

// ---------- MFMA GEMM1 + fused stats1 (sliced atomics) ------------------------------
__global__ __launch_bounds__(256) void gemm1_k(const ushortT* __restrict__ xb,
                                               const ushortT* __restrict__ w1b,
                                               ushortT* __restrict__ t1,
                                               float* __restrict__ p1) {
    __shared__ ushortT As[128 * 40];
    __shared__ ushortT Bs[128 * 40];
    const int t = threadIdx.x;
    const int P0 = blockIdx.x * 128, C0 = blockIdx.y * 128, n = blockIdx.z;
    const int w = t >> 6, lane = t & 63;
    const int mh = (w >> 1) * 64, nh = (w & 1) * 64;
    const int l15 = lane & 15, quad = lane >> 4;
    const int sr = t >> 2, skq = (t & 3) * 8;

    floatx4 acc[4][4];
#pragma unroll
    for (int a = 0; a < 4; a++)
#pragma unroll
        for (int b = 0; b < 4; b++)
#pragma unroll
            for (int e = 0; e < 4; e++) acc[a][b][e] = 0.f;

    for (int kb = 0; kb < 256; kb += 32) {
#pragma unroll
        for (int i = 0; i < 2; i++) {
            int r = sr + i * 64;
            short8 v = *(const short8*)&w1b[(size_t)(C0 + r) * 256 + kb + skq];
            *(short8*)&As[r * 40 + skq] = v;
        }
#pragma unroll
        for (int i = 0; i < 2; i++) {
            int p = sr + i * 64;
            short8 v;
            if (P0 + p < HW) {
                v = *(const short8*)&xb[((size_t)n * HW + P0 + p) * 256 + kb + skq];
            } else {
#pragma unroll
                for (int j = 0; j < 8; j++) v[j] = 0;
            }
            *(short8*)&Bs[p * 40 + skq] = v;
        }
        __syncthreads();
        short8 af[4], bf[4];
#pragma unroll
        for (int mt = 0; mt < 4; mt++)
            af[mt] = *(const short8*)&As[(mh + mt * 16 + l15) * 40 + quad * 8];
#pragma unroll
        for (int nt = 0; nt < 4; nt++)
            bf[nt] = *(const short8*)&Bs[(nh + nt * 16 + l15) * 40 + quad * 8];
#pragma unroll
        for (int mt = 0; mt < 4; mt++)
#pragma unroll
            for (int nt = 0; nt < 4; nt++)
                acc[mt][nt] = __builtin_amdgcn_mfma_f32_16x16x32_bf16(af[mt], bf[nt], acc[mt][nt], 0, 0, 0);
        __syncthreads();
    }
#pragma unroll
    for (int mt = 0; mt < 4; mt++) {
        int c = C0 + mh + mt * 16 + quad * 4;
#pragma unroll
        for (int nt = 0; nt < 4; nt++) {
            int pp = P0 + nh + nt * 16 + l15;
            if (pp < HW) {
                ushort4 o;
                o.x = f2bf(acc[mt][nt][0]); o.y = f2bf(acc[mt][nt][1]);
                o.z = f2bf(acc[mt][nt][2]); o.w = f2bf(acc[mt][nt][3]);
                *(ushort4*)&t1[((size_t)n * HW + pp) * 512 + c] = o;
            }
        }
    }
    // fused stats1 (OOB positions contributed acc==0 -> no effect)
    float* ps = p1 + ((blockIdx.x + blockIdx.z * 25) & (NSLICE - 1)) * 1024;
#pragma unroll
    for (int mt = 0; mt < 4; mt++) {
        int c = C0 + mh + mt * 16 + quad * 4;
#pragma unroll
        for (int e = 0; e < 4; e++) {
            float sv = acc[mt][0][e] + acc[mt][1][e] + acc[mt][2][e] + acc[mt][3][e];
            float qv = acc[mt][0][e] * acc[mt][0][e] + acc[mt][1][e] * acc[mt][1][e]
                     + acc[mt][2][e] * acc[mt][2][e] + acc[mt][3][e] * acc[mt][3][e];
            sv += __shfl_xor(sv, 1); qv += __shfl_xor(qv, 1);
            sv += __shfl_xor(sv, 2); qv += __shfl_xor(qv, 2);
            sv += __shfl_xor(sv, 4); qv += __shfl_xor(qv, 4);
            sv += __shfl_xor(sv, 8); qv += __shfl_xor(qv, 8);
            if (l15 == 0) {
                atomicAdd(&ps[c + e], sv);
                atomicAdd(&ps[512 + c + e], qv);
            }
        }
    }
}

// ---------- gconv: 4 groups/block, coalesced 128B reads, fused BN1+ReLU + stats2 ----
__global__ __launch_bounds__(256) void gconv_k(const ushortT* __restrict__ t1,
                                               const ushortT* __restrict__ w3b,
                                               const float* __restrict__ p1,
                                               const float* __restrict__ g1,
                                               const float* __restrict__ b1,
                                               ushortT* __restrict__ t2,
                                               float* __restrict__ p2) {
    // 8 planes (chq) x 590 pos (10 rows x 59 padded cols) x 8 ch; 16B-aligned frags
    __shared__ ushortT tile[8 * 590 * 8];
    __shared__ float scs[64], shs[64];
    const int t = threadIdx.x;
    const int rt = blockIdx.x, gg = blockIdx.y, n = blockIdx.z;
    const int r0 = rt * 8;

    if (t < 64) {
        int c = gg * 64 + t;
        float S = 0.f, Q = 0.f;
#pragma unroll
        for (int s = 0; s < NSLICE; s++) {
            S += p1[s * 1024 + c];
            Q += p1[s * 1024 + 512 + c];
        }
        float m = S * (1.f / NPOS);
        float var = Q * (1.f / NPOS) - m * m;
        float sc = g1[c] * rsqrtf(var + 1e-5f);
        scs[t] = sc; shs[t] = b1[c] - m * sc;
    }
    __syncthreads();

    const int chq = t & 7;
    float sc8[8], sh8[8];
#pragma unroll
    for (int j = 0; j < 8; j++) { sc8[j] = scs[chq * 8 + j]; sh8[j] = shs[chq * 8 + j]; }

    const ushortT* src = t1 + (size_t)n * HW * 512 + gg * 64 + chq * 8;
    for (int idx = t; idx < 4640; idx += 256) {
        int pos = idx >> 3;
        int row = pos / 58, col = pos - row * 58;   // row 0..9, col 0..57
        int ir = r0 - 1 + row, icl = col - 1;
        short8 o;
        if (ir >= 0 && ir < 56 && icl >= 0 && icl < 56) {
            short8 v = *(const short8*)&src[(size_t)(ir * 56 + icl) * 512];
#pragma unroll
            for (int j = 0; j < 8; j++)
                o[j] = (short)f2bf(fmaxf(fmaf(sc8[j], bf2f((ushortT)v[j]), sh8[j]), 0.f));
        } else {
#pragma unroll
            for (int j = 0; j < 8; j++) o[j] = 0;
        }
        *(short8*)&tile[((chq * 590) + row * 59 + col) * 8] = o;
    }
    __syncthreads();

    const int w = t >> 6, lane = t & 63;
    const int l15 = lane & 15, quad = lane >> 4;
    const int qh = quad >> 1, ql = quad & 1;
    const int g = gg * 4 + w;                  // wave owns one group

    short8 af[5];
    int drv[5], dcv[5];
#pragma unroll
    for (int s = 0; s < 5; s++) {
        int shift = 2 * s + qh;
        af[s] = *(const short8*)&w3b[((g * 10 + shift) * 16 + l15) * 16 + ql * 8];
        if (shift == 9) shift = 8;             // dummy half: valid addr, zero weights
        drv[s] = shift / 3; dcv[s] = shift - drv[s] * 3;
    }

    const int pr = l15 >> 2, pc = l15 & 3;
    const int plane = (w * 2 + ql) * 590;
    float s4[4] = {0.f, 0.f, 0.f, 0.f}, q4[4] = {0.f, 0.f, 0.f, 0.f};

#pragma unroll
    for (int rh = 0; rh < 2; rh++) {
        const int rbase = rh * 4 + pr;
        floatx4 acc[14];
#pragma unroll
        for (int ct = 0; ct < 14; ct++)
#pragma unroll
            for (int e = 0; e < 4; e++) acc[ct][e] = 0.f;

#pragma unroll
        for (int ct = 0; ct < 14; ct++) {
            int colb = ct * 4 + pc;
#pragma unroll
            for (int s = 0; s < 5; s++) {
                short8 bfv = *(const short8*)&tile[(plane + (rbase + drv[s]) * 59 + colb + dcv[s]) * 8];
                acc[ct] = __builtin_amdgcn_mfma_f32_16x16x32_bf16(af[s], bfv, acc[ct], 0, 0, 0);
            }
        }
#pragma unroll
        for (int ct = 0; ct < 14; ct++) {
            int pos = (r0 + rh * 4 + pr) * 56 + ct * 4 + pc;
            ushort4 o;
            o.x = f2bf(acc[ct][0]); o.y = f2bf(acc[ct][1]);
            o.z = f2bf(acc[ct][2]); o.w = f2bf(acc[ct][3]);
            *(ushort4*)&t2[((size_t)n * HW + pos) * 512 + g * 16 + quad * 4] = o;
#pragma unroll
            for (int e = 0; e < 4; e++) {
                float a = acc[ct][e];
                s4[e] += a; q4[e] += a * a;
            }
        }
    }
    float* ps = p2 + ((blockIdx.x + blockIdx.z * 7) & (NSLICE - 1)) * 1024;
#pragma unroll
    for (int e = 0; e < 4; e++) {
        float sv = s4[e], qv = q4[e];
        sv += __shfl_xor(sv, 1); qv += __shfl_xor(qv, 1);
        sv += __shfl_xor(sv, 2); qv += __shfl_xor(qv, 2);
        sv += __shfl_xor(sv, 4); qv += __shfl_xor(qv, 4);
        sv += __shfl_xor(sv, 8); qv += __shfl_xor(qv, 8);
        if (l15 == 0) {
            atomicAdd(&ps[g * 16 + quad * 4 + e], sv);
            atomicAdd(&ps[512 + g * 16 + quad * 4 + e], qv);
        }
    }
}

// ---------- MFMA GEMM3: full 256-ch tile, fused BN2+ReLU on input + stats3 ----------
__global__ __launch_bounds__(256) void gemm3_k(const ushortT* __restrict__ t2,
                                               const ushortT* __restrict__ wab,
                                               const float* __restrict__ p2,
                                               const float* __restrict__ g3,
                                               const float* __restrict__ b3,
                                               ushortT* __restrict__ t3,
                                               float* __restrict__ p3) {
    __shared__ ushortT As[256 * 40];
    __shared__ ushortT Bs[64 * 40];
    __shared__ float2 scsh[512];
    const int t = threadIdx.x;
    const int P0 = blockIdx.x * 64, n = blockIdx.y;   // 49*64 == 3136 exactly, no OOB
    const int w = t >> 6, lane = t & 63;
    const int mh = w * 64;
    const int l15 = lane & 15, quad = lane >> 4;
    const int sr = t >> 2, skq = (t & 3) * 8;

#pragma unroll
    for (int i = 0; i < 2; i++) {
        int c = t + i * 256;
        float S = 0.f, Q = 0.f;
#pragma unroll
        for (int s = 0; s < NSLICE; s++) {
            S += p2[s * 1024 + c];
            Q += p2[s * 1024 + 512 + c];
        }
        float m = S * (1.f / NPOS);
        float var = Q * (1.f / NPOS) - m * m;
        float sc = g3[c] * rsqrtf(var + 1e-5f);
        scsh[c] = make_float2(sc, b3[c] - m * sc);
    }
    __syncthreads();

    floatx4 acc[4][4];
#pragma unroll
    for (int a = 0; a < 4; a++)
#pragma unroll
        for (int b = 0; b < 4; b++)
#pragma unroll
            for (int e = 0; e < 4; e++) acc[a][b][e] = 0.f;

    for (int kb = 0; kb < 512; kb += 32) {
#pragma unroll
        for (int i = 0; i < 4; i++) {
            int r = sr + i * 64;
            short8 v = *(const short8*)&wab[(size_t)r * 512 + kb + skq];
            *(short8*)&As[r * 40 + skq] = v;
        }
        {
            int p = sr;
            short8 v = *(const short8*)&t2[((size_t)n * HW + P0 + p) * 512 + kb + skq];
            short8 o;
#pragma unroll
            for (int j = 0; j < 8; j++) {
                float2 ss = scsh[kb + skq + j];
                o[j] = (short)f2bf(fmaxf(fmaf(ss.x, bf2f((ushortT)v[j]), ss.y), 0.f));
            }
            *(short8*)&Bs[p * 40 + skq] = o;
        }
        __syncthreads();
        short8 af[4], bf[4];
#pragma unroll
        for (int mt = 0; mt < 4; mt++)
            af[mt] = *(const short8*)&As[(mh + mt * 16 + l15) * 40 + quad * 8];
#pragma unroll
        for (int nt = 0; nt < 4; nt++)
            bf[nt] = *(const short8*)&Bs[(nt * 16 + l15) * 40 + quad * 8];
#pragma unroll
        for (int mt = 0; mt < 4; mt++)
#pragma unroll
            for (int nt = 0; nt < 4; nt++)
                acc[mt][nt] = __builtin_amdgcn_mfma_f32_16x16x32_bf16(af[mt], bf[nt], acc[mt][nt], 0, 0, 0);
        __syncthreads();
    }
#pragma unroll
    for (int mt = 0; mt < 4; mt++) {
        int c = mh + mt * 16 + quad * 4;
#pragma unroll
        for (int nt = 0; nt < 4; nt++) {
            int pp = P0 + nt * 16 + l15;
            ushort4 o;
            o.x = f2bf(acc[mt][nt][0]); o.y = f2bf(acc[mt][nt][1]);
            o.z = f2bf(acc[mt][nt][2]); o.w = f2bf(acc[mt][nt][3]);
            *(ushort4*)&t3[((size_t)n * HW + pp) * 256 + c] = o;
        }
    }
    float* ps = p3 + ((blockIdx.x + blockIdx.y * 49) & (NSLICE - 1)) * 512;
#pragma unroll
    for (int mt = 0; mt < 4; mt++) {
        int c = mh + mt * 16 + quad * 4;
#pragma unroll
        for (int e = 0; e < 4; e++) {
            float sv = acc[mt][0][e] + acc[mt][1][e] + acc[mt][2][e] + acc[mt][3][e];
            float qv = acc[mt][0][e] * acc[mt][0][e] + acc[mt][1][e] * acc[mt][1][e]
                     + acc[mt][2][e] * acc[mt][2][e] + acc[mt][3][e] * acc[mt][3][e];
            sv += __shfl_xor(sv, 1); qv += __shfl_xor(qv, 1);
            sv += __shfl_xor(sv, 2); qv += __shfl_xor(qv, 2);
            sv += __shfl_xor(sv, 4); qv += __shfl_xor(qv, 4);
            sv += __shfl_xor(sv, 8); qv += __shfl_xor(qv, 8);
            if (l15 == 0) {
                atomicAdd(&ps[c + e], sv);
                atomicAdd(&ps[256 + c + e], qv);
            }
        }
    }
}

// ---------- final: out[n][c][p] = relu(bn3(t3[n][p][c]) + x[n][c][p]) ---------------
__global__ __launch_bounds__(256) void final_k(const ushortT* __restrict__ t3,
                                               const float* __restrict__ x,
                                               const float* __restrict__ p3,
                                               const float* __restrict__ ga,
                                               const float* __restrict__ ba,
                                               float* __restrict__ out) {
    __shared__ float tf[64 * 65];
    __shared__ float scs[64], shs[64];
    const int t = threadIdx.x;
    const int p0 = blockIdx.x * 64, c0 = blockIdx.y * 64, n = blockIdx.z;
    if (t < 64) {
        int c = c0 + t;
        float S = 0.f, Q = 0.f;
#pragma unroll
        for (int s = 0; s < NSLICE; s++) {
            S += p3[s * 512 + c];
            Q += p3[s * 512 + 256 + c];
        }
        float m = S * (1.f / NPOS);
        float var = Q * (1.f / NPOS) - m * m;
        float sc = ga[c] * rsqrtf(var + 1e-5f);
        scs[t] = sc; shs[t] = ba[c] - m * sc;
    }
    __syncthreads();
#pragma unroll
    for (int i = 0; i < 4; i++) {
        int idx = t + i * 256;
        int p = idx >> 4, cq = (idx & 15) * 4;
        ushort4 v = *(const ushort4*)&t3[((size_t)n * HW + p0 + p) * 256 + c0 + cq];
        tf[(cq + 0) * 65 + p] = fmaf(scs[cq + 0], bf2f(v.x), shs[cq + 0]);
        tf[(cq + 1) * 65 + p] = fmaf(scs[cq + 1], bf2f(v.y), shs[cq + 1]);
        tf[(cq + 2) * 65 + p] = fmaf(scs[cq + 2], bf2f(v.z), shs[cq + 2]);
        tf[(cq + 3) * 65 + p] = fmaf(scs[cq + 3], bf2f(v.w), shs[cq + 3]);
    }
    __syncthreads();
#pragma unroll
    for (int i = 0; i < 4; i++) {
        int idx = t + i * 256;
        int c = idx >> 4, pq = (idx & 15) * 4;
        size_t off = ((size_t)n * 256 + c0 + c) * HW + p0 + pq;
        float4 xv = *(const float4*)&x[off];
        float4 o;
        o.x = fmaxf(tf[c * 65 + pq + 0] + xv.x, 0.f);
        o.y = fmaxf(tf[c * 65 + pq + 1] + xv.y, 0.f);
        o.z = fmaxf(tf[c * 65 + pq + 2] + xv.z, 0.f);
        o.w = fmaxf(tf[c * 65 + pq + 3] + xv.w, 0.f);
        *(float4*)&out[off] = o;
    }
}

extern "C" void kernel_launch(void* const* d_in, const int* in_sizes, int n_in,
                              void* d_out, int out_size, void* d_ws, size_t ws_size,
                              hipStream_t stream) {
    const float* x  = (const float*)d_in[0];
    const float* w1 = (const float*)d_in[1];
    const float* g1 = (const float*)d_in[2];
    const float* b1 = (const float*)d_in[3];
    const float* w3 = (const float*)d_in[4];
    const float* g3 = (const float*)d_in[5];
    const float* b3 = (const float*)d_in[6];
    const float* wa = (const float*)d_in[7];
    const float* ga = (const float*)d_in[8];
    const float* ba = (const float*)d_in[9];
    float* out = (float*)d_out;

    char* ws = (char*)d_ws;
    // Region 1 (102,760,448 B): t1, later reused as t3
    ushortT* t1 = (ushortT*)ws;
    ushortT* t3 = t1;
    // Region 2 (102,760,448 B): xb (first 51 MB), later overwritten by t2
    ushortT* xb = (ushortT*)(ws + 102760448);
    ushortT* t2 = (ushortT*)(ws + 102760448);
    ushortT* w1b = (ushortT*)(ws + 205520896);
    ushortT* wab = (ushortT*)(ws + 205783040);
    ushortT* w3b = (ushortT*)(ws + 206045184);
    float* partials = (float*)(ws + 206209024);
    float* pt1 = partials;                 // 32 x 1024
    float* pt2 = partials + 32 * 1024;     // 32 x 1024
    float* pt3 = partials + 64 * 1024;     // 32 x 512

    prep_k<<<512, 256, 0, stream>>>(w1, w3, wa, w1b, wab, w3b, partials);
    transx_k<<<dim3(49, 4, 32), 256, 0, stream>>>(x, xb);
    gemm1_k<<<dim3(25, 4, 32), 256, 0, stream>>>(xb, w1b, t1, pt1);
    gconv_k<<<dim3(7, 8, 32), 256, 0, stream>>>(t1, w3b, pt1, g1, b1, t2, pt2);
    gemm3_k<<<dim3(49, 32), 256, 0, stream>>>(t2, wab, pt2, g3, b3, t3, pt3);
    final_k<<<dim3(49, 4, 32), 256, 0, stream>>>(t3, x, pt3, ga, ba, out);
}